// Round 1
// baseline (477.471 us; speedup 1.0000x reference)
//
#include <hip/hip_runtime.h>
#include <math.h>

#define Bz 32
#define Lz 2048
#define Hz 768
#define Tz 12
#define Ez 7
#define EMPTYIDX 6
#define NCOL 24          // T*2 logit columns per batch
#define LCHUNK 128
#define NCHUNK 16        // Lz / LCHUNK

// ---------------- kernel 0: bin (b,t) pairs by module index e ----------------
__global__ void k0_compact(const int* __restrict__ midx,
                           int* __restrict__ off, int* __restrict__ items) {
    __shared__ int cnt[Ez];
    __shared__ int offs[Ez + 1];
    int tid = threadIdx.x;                 // 384 threads, one per (b,t)
    if (tid < Ez) cnt[tid] = 0;
    __syncthreads();
    int e = midx[tid];
    e = min(max(e, 0), Ez - 1);
    int r = atomicAdd(&cnt[e], 1);
    __syncthreads();
    if (tid == 0) {
        int acc = 0;
        for (int j = 0; j < Ez; ++j) { offs[j] = acc; acc += cnt[j]; }
        offs[Ez] = acc;
    }
    __syncthreads();
    items[offs[e] + r] = tid;
    if (tid <= Ez) off[tid] = offs[tid];
}

// ---------------- kernel 1: grouped matvec cW = ctx @ W[e], then v = cW*spanw
// grid = Ez(7) * ZCH(6) * RG(8) = 336 blocks, 128 threads (z-chunk of 128)
#define K1_T 128
#define K1_ZCH 6
#define K1_RG 8
#define K1_RB 8
__global__ void k1_cw(const float* __restrict__ seq, const float* __restrict__ W,
                      const float* __restrict__ spanw, const int* __restrict__ turns,
                      const int* __restrict__ off, const int* __restrict__ items,
                      float* __restrict__ v) {
    int bx  = blockIdx.x;
    int e   = bx % Ez;
    int zc  = (bx / Ez) % K1_ZCH;
    int rgi = bx / (Ez * K1_ZCH);          // 0..7
    int tid = threadIdx.x;
    int z   = zc * K1_T + tid;             // 0..767
    int off0 = off[e], off1 = off[e + 1];
    int cntE = off1 - off0;
    float sw0 = spanw[(e * Hz + z) * 2 + 0];
    float sw1 = spanw[(e * Hz + z) * 2 + 1];
    __shared__ float ctx[K1_RB][Hz];       // 24 KB
    __shared__ int   rowi[K1_RB];
    __shared__ int   rowst[K1_RB];
    const float* Wbase = W + (size_t)e * Hz * Hz;

    for (int r0 = rgi * K1_RB; r0 < cntE; r0 += K1_RG * K1_RB) {
        int nb = min(K1_RB, cntE - r0);
        if (tid < nb) {
            int i = items[off0 + r0 + tid];
            rowi[tid] = i;
            int st = turns[2 * i];
            rowst[tid] = min(max(st, 0), Lz - 1);
        }
        __syncthreads();
        // stage ctx rows (float4, coalesced)
        int nf4 = nb * (Hz / 4);
        for (int g = tid; g < nf4; g += K1_T) {
            int rr = g / (Hz / 4);
            int h4 = g % (Hz / 4);
            int i  = rowi[rr];
            int b  = i / Tz;
            const float* src = seq + ((size_t)(b * Lz + rowst[rr])) * Hz;
            *(float4*)&ctx[rr][h4 * 4] = *(const float4*)&src[h4 * 4];
        }
        __syncthreads();
        float acc[K1_RB];
#pragma unroll
        for (int r = 0; r < K1_RB; ++r) acc[r] = 0.f;
        if (nb == K1_RB) {
            for (int h = 0; h < Hz; h += 4) {
                float w0 = Wbase[(size_t)(h + 0) * Hz + z];
                float w1 = Wbase[(size_t)(h + 1) * Hz + z];
                float w2 = Wbase[(size_t)(h + 2) * Hz + z];
                float w3 = Wbase[(size_t)(h + 3) * Hz + z];
#pragma unroll
                for (int r = 0; r < K1_RB; ++r) {
                    float4 c4 = *(const float4*)&ctx[r][h];
                    acc[r] = fmaf(c4.w, w3, fmaf(c4.z, w2, fmaf(c4.y, w1, fmaf(c4.x, w0, acc[r]))));
                }
            }
        } else {
            for (int h = 0; h < Hz; h += 4) {
                float w0 = Wbase[(size_t)(h + 0) * Hz + z];
                float w1 = Wbase[(size_t)(h + 1) * Hz + z];
                float w2 = Wbase[(size_t)(h + 2) * Hz + z];
                float w3 = Wbase[(size_t)(h + 3) * Hz + z];
                for (int r = 0; r < nb; ++r) {
                    float4 c4 = *(const float4*)&ctx[r][h];
                    acc[r] = fmaf(c4.w, w3, fmaf(c4.z, w2, fmaf(c4.y, w1, fmaf(c4.x, w0, acc[r]))));
                }
            }
        }
        for (int rr = 0; rr < nb; ++rr) {
            int i = rowi[rr];
            int b = i / Tz, t = i % Tz;
            size_t vbase = ((size_t)(b * NCOL + t * 2)) * Hz + z;  // layout [b][col][z]
            v[vbase]      = acc[rr] * sw0;
            v[vbase + Hz] = acc[rr] * sw1;
        }
        __syncthreads();
    }
}

// ---------------- kernel 2: logits GEMM (128 l-rows x 24 cols) + block logsumexp partials
// grid = Bz*NCHUNK = 512 blocks, 256 threads
#define BK 32
__global__ void k2_logits(const float* __restrict__ seq, const float* __restrict__ v,
                          float* __restrict__ pm, float* __restrict__ ps) {
    int bx = blockIdx.x;
    int b  = bx / NCHUNK;
    int ch = bx % NCHUNK;
    int l0 = ch * LCHUNK;
    int tid = threadIdx.x;
    int rg = tid >> 3;                     // 0..31  -> rows rg*4..rg*4+3
    int cg = tid & 7;                      // 0..7   -> cols cg*3..cg*3+2
    __shared__ float at[LCHUNK][BK + 4];   // 18 KB, padded stride 36 (144B, 16B-aligned)
    __shared__ float vt[NCOL][BK + 4];     // 3.4 KB
    __shared__ float red_m[NCOL][33];
    __shared__ float red_s[NCOL][33];
    float acc[4][3];
#pragma unroll
    for (int r = 0; r < 4; ++r)
#pragma unroll
        for (int j = 0; j < 3; ++j) acc[r][j] = 0.f;

    const float* A = seq + ((size_t)b * Lz + l0) * Hz;
    const float* V = v + (size_t)b * NCOL * Hz;

    for (int k0 = 0; k0 < Hz; k0 += BK) {
#pragma unroll
        for (int p = 0; p < 4; ++p) {
            int j  = tid + p * 256;        // 0..1023
            int r  = j >> 3, c4 = j & 7;
            float4 x = *(const float4*)&A[(size_t)r * Hz + k0 + c4 * 4];
            *(float4*)&at[r][c4 * 4] = x;
        }
        if (tid < 192) {
            int c = tid >> 3, q = tid & 7;
            *(float4*)&vt[c][q * 4] = *(const float4*)&V[(size_t)c * Hz + k0 + q * 4];
        }
        __syncthreads();
#pragma unroll
        for (int kk = 0; kk < BK; kk += 4) {
            float4 a0 = *(const float4*)&at[rg * 4 + 0][kk];
            float4 a1 = *(const float4*)&at[rg * 4 + 1][kk];
            float4 a2 = *(const float4*)&at[rg * 4 + 2][kk];
            float4 a3 = *(const float4*)&at[rg * 4 + 3][kk];
            float4 v0 = *(const float4*)&vt[cg * 3 + 0][kk];
            float4 v1 = *(const float4*)&vt[cg * 3 + 1][kk];
            float4 v2 = *(const float4*)&vt[cg * 3 + 2][kk];
#define DOT(ACC, AV, VV) ACC = fmaf(AV.w, VV.w, fmaf(AV.z, VV.z, fmaf(AV.y, VV.y, fmaf(AV.x, VV.x, ACC))))
            DOT(acc[0][0], a0, v0); DOT(acc[0][1], a0, v1); DOT(acc[0][2], a0, v2);
            DOT(acc[1][0], a1, v0); DOT(acc[1][1], a1, v1); DOT(acc[1][2], a1, v2);
            DOT(acc[2][0], a2, v0); DOT(acc[2][1], a2, v1); DOT(acc[2][2], a2, v2);
            DOT(acc[3][0], a3, v0); DOT(acc[3][1], a3, v1); DOT(acc[3][2], a3, v2);
#undef DOT
        }
        __syncthreads();
    }
    // local online-softmax over this thread's 4 rows, then combine over 32 row-groups
#pragma unroll
    for (int j = 0; j < 3; ++j) {
        int c = cg * 3 + j;
        float m = fmaxf(fmaxf(acc[0][j], acc[1][j]), fmaxf(acc[2][j], acc[3][j]));
        float s = expf(acc[0][j] - m) + expf(acc[1][j] - m) +
                  expf(acc[2][j] - m) + expf(acc[3][j] - m);
        red_m[c][rg] = m;
        red_s[c][rg] = s;
    }
    __syncthreads();
    if (tid < NCOL) {
        int c = tid;
        float m = red_m[c][0];
        for (int r = 1; r < 32; ++r) m = fmaxf(m, red_m[c][r]);
        float s = 0.f;
        for (int r = 0; r < 32; ++r) s += red_s[c][r] * expf(red_m[c][r] - m);
        pm[((size_t)b * NCOL + c) * NCHUNK + ch] = m;
        ps[((size_t)b * NCOL + c) * NCHUNK + ch] = s;
    }
}

// ---------------- kernel 3: picked logits (dot at the target row) ----------------
__global__ void k3_picked(const float* __restrict__ seq, const float* __restrict__ v,
                          const int* __restrict__ kps, float* __restrict__ picked) {
    int i = blockIdx.x;                    // 0..383
    int b = i / Tz, t = i % Tz;
    int lane = threadIdx.x;                // 64
    for (int k = 0; k < 2; ++k) {
        int tgt  = kps[2 * i + k];
        int safe = min(max(tgt, 0), Lz - 1);
        const float* srow = seq + ((size_t)b * Lz + safe) * Hz;
        const float* vcol = v + ((size_t)(b * NCOL + t * 2 + k)) * Hz;
        float sum = 0.f;
#pragma unroll
        for (int q = 0; q < Hz / 64; ++q) {
            int z = lane + q * 64;
            sum = fmaf(srow[z], vcol[z], sum);
        }
        for (int o = 32; o > 0; o >>= 1) sum += __shfl_down(sum, o, 64);
        if (lane == 0) picked[b * NCOL + t * 2 + k] = sum;
    }
}

// ---------------- kernel 4: combine partials -> ce -> masked-mean loss ----------------
__global__ void k4_final(const int* __restrict__ midx, const int* __restrict__ turns,
                         const int* __restrict__ kps,
                         const float* __restrict__ pm, const float* __restrict__ ps,
                         const float* __restrict__ picked, float* __restrict__ out) {
    int tid = threadIdx.x;                 // 384 threads, one per (b,t)
    int i = tid;
    int b = i / Tz, t = i % Tz;
    int e = midx[i];
    float modm  = (e != EMPTYIDX) ? 1.f : 0.f;
    float tmask = (turns[2 * i] >= 0) ? 1.f : 0.f;
    float ce[2];
#pragma unroll
    for (int k = 0; k < 2; ++k) {
        int c = t * 2 + k;
        const float* pmr = pm + ((size_t)b * NCOL + c) * NCHUNK;
        const float* psr = ps + ((size_t)b * NCOL + c) * NCHUNK;
        float m = pmr[0];
        for (int chn = 1; chn < NCHUNK; ++chn) m = fmaxf(m, pmr[chn]);
        float s = 0.f;
        for (int chn = 0; chn < NCHUNK; ++chn) s += psr[chn] * expf(pmr[chn] - m);
        float lse = m + logf(s);
        int tgt = kps[2 * i + k];
        ce[k] = (tgt >= 0) ? (lse - picked[b * NCOL + c]) : 0.f;
    }
    float contrib = 0.5f * (ce[0] + ce[1]) * modm * tmask;

    __shared__ float wsum[6], wmask[6];
    float sl = contrib, sm = tmask;
    for (int o = 32; o > 0; o >>= 1) {
        sl += __shfl_down(sl, o, 64);
        sm += __shfl_down(sm, o, 64);
    }
    int w = tid >> 6, lane = tid & 63;
    if (lane == 0) { wsum[w] = sl; wmask[w] = sm; }
    __syncthreads();
    if (tid == 0) {
        float a = 0.f, mk = 0.f;
        for (int ww = 0; ww < 6; ++ww) { a += wsum[ww]; mk += wmask[ww]; }
        out[0] = a / mk;
    }
}

extern "C" void kernel_launch(void* const* d_in, const int* in_sizes, int n_in,
                              void* d_out, int out_size, void* d_ws, size_t ws_size,
                              hipStream_t stream) {
    const float* seq   = (const float*)d_in[0];  // (32,2048,768)
    const float* W     = (const float*)d_in[1];  // (7,768,768)
    const float* spanw = (const float*)d_in[2];  // (7,768,2)
    const int*   turns = (const int*)d_in[3];    // (32,12,2)
    const int*   kps   = (const int*)d_in[4];    // (32,12,2)
    const int*   midx  = (const int*)d_in[5];    // (32,12)
    float* out = (float*)d_out;

    char* ws = (char*)d_ws;
    int*   off    = (int*)(ws + 0);                          // 8 ints
    int*   items  = (int*)(ws + 64);                         // 384 ints
    float* v      = (float*)(ws + 2048);                     // 32*24*768 f32 = 2359296 B
    float* pm     = (float*)(ws + 2048 + 2359296);           // 32*24*16 f32 = 49152 B
    float* ps     = (float*)(ws + 2048 + 2359296 + 49152);   // 49152 B
    float* picked = (float*)(ws + 2048 + 2359296 + 98304);   // 3072 B

    hipLaunchKernelGGL(k0_compact, dim3(1), dim3(Bz * Tz), 0, stream, midx, off, items);
    hipLaunchKernelGGL(k1_cw, dim3(Ez * K1_ZCH * K1_RG), dim3(K1_T), 0, stream,
                       seq, W, spanw, turns, off, items, v);
    hipLaunchKernelGGL(k2_logits, dim3(Bz * NCHUNK), dim3(256), 0, stream, seq, v, pm, ps);
    hipLaunchKernelGGL(k3_picked, dim3(Bz * Tz), dim3(64), 0, stream, seq, v, kps, picked);
    hipLaunchKernelGGL(k4_final, dim3(1), dim3(Bz * Tz), 0, stream,
                       midx, turns, kps, pm, ps, picked, out);
}

// Round 2
// 370.678 us; speedup vs baseline: 1.2881x; 1.2881x over previous
//
#include <hip/hip_runtime.h>
#include <math.h>

#define Bz 32
#define Lz 2048
#define Hz 768
#define Tz 12
#define Ez 7
#define EMPTYIDX 6
#define NCOL 24          // T*2 logit columns per batch
#define LCHUNK 128
#define NCHUNK 16        // Lz / LCHUNK

// ---------------- kernel 0: bin (b,t) pairs by module index e ----------------
__global__ void k0_compact(const int* __restrict__ midx,
                           int* __restrict__ off, int* __restrict__ items) {
    __shared__ int cnt[Ez];
    __shared__ int offs[Ez + 1];
    int tid = threadIdx.x;                 // 384 threads, one per (b,t)
    if (tid < Ez) cnt[tid] = 0;
    __syncthreads();
    int e = midx[tid];
    e = min(max(e, 0), Ez - 1);
    int r = atomicAdd(&cnt[e], 1);
    __syncthreads();
    if (tid == 0) {
        int acc = 0;
        for (int j = 0; j < Ez; ++j) { offs[j] = acc; acc += cnt[j]; }
        offs[Ez] = acc;
    }
    __syncthreads();
    items[offs[e] + r] = tid;
    if (tid <= Ez) off[tid] = offs[tid];
}

// ---------------- kernel 1a: cW partial dots, H split across blocks ----------
// grid = Ez(7) * ZC(3) * HC(16) = 336 blocks, 256 threads.
// Each block owns a 48h x 256z slab of W[e], read from HBM exactly once into
// registers (48 independent loads in flight). ctx values are wave-uniform ->
// scalar loads on the SMEM pipe, zero LDS. Partials accumulated with
// atomicAdd into cW (zeroed via hipMemsetAsync).
#define K1A_ZC 3
#define K1A_HB 48
#define K1A_HC 16
__global__ void k1a_cw(const float* __restrict__ seq, const float* __restrict__ W,
                       const int* __restrict__ turns,
                       const int* __restrict__ off, const int* __restrict__ items,
                       float* __restrict__ cW) {
    int bx = blockIdx.x;
    int e  = bx % Ez;
    int zc = (bx / Ez) % K1A_ZC;
    int hc = bx / (Ez * K1A_ZC);           // 0..15
    int z  = zc * 256 + threadIdx.x;       // 0..767
    int h0 = hc * K1A_HB;
    int off0 = off[e];
    int cnt  = off[e + 1] - off0;
    const float* Wb = W + ((size_t)e * Hz + h0) * Hz + z;
    float w[K1A_HB];
#pragma unroll
    for (int j = 0; j < K1A_HB; ++j) w[j] = Wb[(size_t)j * Hz];

    for (int n = 0; n < cnt; ++n) {
        int i  = items[off0 + n];          // wave-uniform
        int b  = i / Tz;
        int st = turns[2 * i];
        st = min(max(st, 0), Lz - 1);
        const float* c = seq + ((size_t)(b * Lz + st)) * Hz + h0;  // uniform -> s_load
        float acc = 0.f;
#pragma unroll
        for (int j = 0; j < K1A_HB; ++j) acc = fmaf(c[j], w[j], acc);
        atomicAdd(&cW[(size_t)i * Hz + z], acc);
    }
}

// ---------------- kernel 1b: v = cW * spanw (elementwise) --------------------
__global__ void k1b_v(const float* __restrict__ cW, const float* __restrict__ spanw,
                      const int* __restrict__ midx, float* __restrict__ v) {
    int idx = blockIdx.x * 256 + threadIdx.x;   // 384*768 = 294912
    int i = idx / Hz;
    int z = idx - i * Hz;
    int e = midx[i];
    e = min(max(e, 0), Ez - 1);
    float cw = cW[idx];
    int b = i / Tz, t = i - b * Tz;
    size_t vb = ((size_t)(b * NCOL + t * 2)) * Hz + z;
    v[vb]      = cw * spanw[(e * Hz + z) * 2 + 0];
    v[vb + Hz] = cw * spanw[(e * Hz + z) * 2 + 1];
}

// ---------------- kernel 2: logits GEMM + block logsumexp partials -----------
// grid = Bz*NCHUNK = 512 blocks, 256 threads. BK=64.
// Thread tile: rows {rg, rg+32, rg+64, rg+96} (consecutive concurrent rows ->
// bank-conflict-free b128 reads with stride-68 rows), cols cg*3..cg*3+2.
#define BK 64
#define ATS (BK + 4)     // 68 floats: 68 mod 32 = 4 -> rg-consecutive reads tile banks
__global__ void k2_logits(const float* __restrict__ seq, const float* __restrict__ v,
                          float* __restrict__ pm, float* __restrict__ ps) {
    int bx = blockIdx.x;
    int b  = bx / NCHUNK;
    int ch = bx % NCHUNK;
    int l0 = ch * LCHUNK;
    int tid = threadIdx.x;
    int rg = tid >> 3;                     // 0..31 -> rows rg + 32*r
    int cg = tid & 7;                      // 0..7  -> cols cg*3..cg*3+2
    __shared__ float at[LCHUNK][ATS];      // 34.8 KB
    __shared__ float vt[NCOL][ATS];        // 6.5 KB
    __shared__ float red_m[NCOL][33];
    __shared__ float red_s[NCOL][33];
    float acc[4][3];
#pragma unroll
    for (int r = 0; r < 4; ++r)
#pragma unroll
        for (int j = 0; j < 3; ++j) acc[r][j] = 0.f;

    const float* A = seq + ((size_t)b * Lz + l0) * Hz;
    const float* V = v + (size_t)b * NCOL * Hz;

    for (int k0 = 0; k0 < Hz; k0 += BK) {
        // stage A: 128 rows x 64 floats = 2048 float4
#pragma unroll
        for (int p = 0; p < 8; ++p) {
            int j  = tid + p * 256;        // 0..2047
            int r  = j >> 4, c4 = j & 15;
            float4 x = *(const float4*)&A[(size_t)r * Hz + k0 + c4 * 4];
            *(float4*)&at[r][c4 * 4] = x;
        }
        // stage V: 24 cols x 64 floats = 384 float4
        {
            int j = tid;
            int c = j >> 4, q = j & 15;
            *(float4*)&vt[c][q * 4] = *(const float4*)&V[(size_t)c * Hz + k0 + q * 4];
            if (tid < 128) {
                j = tid + 256; c = j >> 4; q = j & 15;
                *(float4*)&vt[c][q * 4] = *(const float4*)&V[(size_t)c * Hz + k0 + q * 4];
            }
        }
        __syncthreads();
#pragma unroll
        for (int kk = 0; kk < BK; kk += 4) {
            float4 a0 = *(const float4*)&at[rg +  0][kk];
            float4 a1 = *(const float4*)&at[rg + 32][kk];
            float4 a2 = *(const float4*)&at[rg + 64][kk];
            float4 a3 = *(const float4*)&at[rg + 96][kk];
            float4 v0 = *(const float4*)&vt[cg * 3 + 0][kk];
            float4 v1 = *(const float4*)&vt[cg * 3 + 1][kk];
            float4 v2 = *(const float4*)&vt[cg * 3 + 2][kk];
#define DOT(ACC, AV, VV) ACC = fmaf(AV.w, VV.w, fmaf(AV.z, VV.z, fmaf(AV.y, VV.y, fmaf(AV.x, VV.x, ACC))))
            DOT(acc[0][0], a0, v0); DOT(acc[0][1], a0, v1); DOT(acc[0][2], a0, v2);
            DOT(acc[1][0], a1, v0); DOT(acc[1][1], a1, v1); DOT(acc[1][2], a1, v2);
            DOT(acc[2][0], a2, v0); DOT(acc[2][1], a2, v1); DOT(acc[2][2], a2, v2);
            DOT(acc[3][0], a3, v0); DOT(acc[3][1], a3, v1); DOT(acc[3][2], a3, v2);
#undef DOT
        }
        __syncthreads();
    }
    // local online-softmax over this thread's 4 rows, combine over 32 row-groups
#pragma unroll
    for (int j = 0; j < 3; ++j) {
        int c = cg * 3 + j;
        float m = fmaxf(fmaxf(acc[0][j], acc[1][j]), fmaxf(acc[2][j], acc[3][j]));
        float s = expf(acc[0][j] - m) + expf(acc[1][j] - m) +
                  expf(acc[2][j] - m) + expf(acc[3][j] - m);
        red_m[c][rg] = m;
        red_s[c][rg] = s;
    }
    __syncthreads();
    if (tid < NCOL) {
        int c = tid;
        float m = red_m[c][0];
        for (int r = 1; r < 32; ++r) m = fmaxf(m, red_m[c][r]);
        float s = 0.f;
        for (int r = 0; r < 32; ++r) s += red_s[c][r] * expf(red_m[c][r] - m);
        pm[((size_t)b * NCOL + c) * NCHUNK + ch] = m;
        ps[((size_t)b * NCOL + c) * NCHUNK + ch] = s;
    }
}

// ---------------- kernel 3: picked logits (dot at the target row) ----------------
__global__ void k3_picked(const float* __restrict__ seq, const float* __restrict__ v,
                          const int* __restrict__ kps, float* __restrict__ picked) {
    int i = blockIdx.x;                    // 0..383
    int b = i / Tz, t = i % Tz;
    int lane = threadIdx.x;                // 64
    for (int k = 0; k < 2; ++k) {
        int tgt  = kps[2 * i + k];
        int safe = min(max(tgt, 0), Lz - 1);
        const float* srow = seq + ((size_t)b * Lz + safe) * Hz;
        const float* vcol = v + ((size_t)(b * NCOL + t * 2 + k)) * Hz;
        float sum = 0.f;
#pragma unroll
        for (int q = 0; q < Hz / 64; ++q) {
            int z = lane + q * 64;
            sum = fmaf(srow[z], vcol[z], sum);
        }
        for (int o = 32; o > 0; o >>= 1) sum += __shfl_down(sum, o, 64);
        if (lane == 0) picked[b * NCOL + t * 2 + k] = sum;
    }
}

// ---------------- kernel 4: combine partials -> ce -> masked-mean loss ----------------
__global__ void k4_final(const int* __restrict__ midx, const int* __restrict__ turns,
                         const int* __restrict__ kps,
                         const float* __restrict__ pm, const float* __restrict__ ps,
                         const float* __restrict__ picked, float* __restrict__ out) {
    int tid = threadIdx.x;                 // 384 threads, one per (b,t)
    int i = tid;
    int b = i / Tz, t = i % Tz;
    int e = midx[i];
    float modm  = (e != EMPTYIDX) ? 1.f : 0.f;
    float tmask = (turns[2 * i] >= 0) ? 1.f : 0.f;
    float ce[2];
#pragma unroll
    for (int k = 0; k < 2; ++k) {
        int c = t * 2 + k;
        const float* pmr = pm + ((size_t)b * NCOL + c) * NCHUNK;
        const float* psr = ps + ((size_t)b * NCOL + c) * NCHUNK;
        float m = pmr[0];
        for (int chn = 1; chn < NCHUNK; ++chn) m = fmaxf(m, pmr[chn]);
        float s = 0.f;
        for (int chn = 0; chn < NCHUNK; ++chn) s += psr[chn] * expf(pmr[chn] - m);
        float lse = m + logf(s);
        int tgt = kps[2 * i + k];
        ce[k] = (tgt >= 0) ? (lse - picked[b * NCOL + c]) : 0.f;
    }
    float contrib = 0.5f * (ce[0] + ce[1]) * modm * tmask;

    __shared__ float wsum[6], wmask[6];
    float sl = contrib, sm = tmask;
    for (int o = 32; o > 0; o >>= 1) {
        sl += __shfl_down(sl, o, 64);
        sm += __shfl_down(sm, o, 64);
    }
    int w = tid >> 6, lane = tid & 63;
    if (lane == 0) { wsum[w] = sl; wmask[w] = sm; }
    __syncthreads();
    if (tid == 0) {
        float a = 0.f, mk = 0.f;
        for (int ww = 0; ww < 6; ++ww) { a += wsum[ww]; mk += wmask[ww]; }
        out[0] = a / mk;
    }
}

extern "C" void kernel_launch(void* const* d_in, const int* in_sizes, int n_in,
                              void* d_out, int out_size, void* d_ws, size_t ws_size,
                              hipStream_t stream) {
    const float* seq   = (const float*)d_in[0];  // (32,2048,768)
    const float* W     = (const float*)d_in[1];  // (7,768,768)
    const float* spanw = (const float*)d_in[2];  // (7,768,2)
    const int*   turns = (const int*)d_in[3];    // (32,12,2)
    const int*   kps   = (const int*)d_in[4];    // (32,12,2)
    const int*   midx  = (const int*)d_in[5];    // (32,12)
    float* out = (float*)d_out;

    char* ws = (char*)d_ws;
    int*   off    = (int*)(ws + 0);                    // 8 ints
    int*   items  = (int*)(ws + 64);                   // 384 ints
    float* cW     = (float*)(ws + 2048);               // 384*768 f32   = 1,179,648 B
    float* v      = (float*)(ws + 2048 + 1179648);     // 32*24*768 f32 = 2,359,296 B
    float* pm     = (float*)(ws + 2048 + 1179648 + 2359296);            // 49,152 B
    float* ps     = (float*)(ws + 2048 + 1179648 + 2359296 + 49152);    // 49,152 B
    float* picked = (float*)(ws + 2048 + 1179648 + 2359296 + 98304);    // 3,072 B

    hipMemsetAsync(cW, 0, (size_t)384 * Hz * sizeof(float), stream);
    hipLaunchKernelGGL(k0_compact, dim3(1), dim3(Bz * Tz), 0, stream, midx, off, items);
    hipLaunchKernelGGL(k1a_cw, dim3(Ez * K1A_ZC * K1A_HC), dim3(256), 0, stream,
                       seq, W, turns, off, items, cW);
    hipLaunchKernelGGL(k1b_v, dim3((384 * Hz) / 256), dim3(256), 0, stream,
                       cW, spanw, midx, v);
    hipLaunchKernelGGL(k2_logits, dim3(Bz * NCHUNK), dim3(256), 0, stream, seq, v, pm, ps);
    hipLaunchKernelGGL(k3_picked, dim3(Bz * Tz), dim3(64), 0, stream, seq, v, kps, picked);
    hipLaunchKernelGGL(k4_final, dim3(1), dim3(Bz * Tz), 0, stream,
                       midx, turns, kps, pm, ps, picked, out);
}